// Round 1
// baseline (251.334 us; speedup 1.0000x reference)
//
#include <hip/hip_runtime.h>
#include <hip/hip_cooperative_groups.h>

namespace cg = cooperative_groups;

// out = A @ x, COO (rows sorted), E=800000, N=50000, D=128.
// R9: fuse {memset(out), prep(bf16-convert + (col,val) pack), agg} into ONE
// cooperative kernel with a grid.sync() between prep and agg.
//  - saves the memset dispatch + 2 inter-kernel gaps (~6-12 us)
//  - agg phase is the R6-proven static edge-balanced body, verbatim, over a
//    balanced contiguous partition of 64-edge groups across 4096 waves
//    (fewer spans than before -> fewer boundary atomics)
//  - diagnostic: the fused dispatch (~55-65 us) exceeds the harness fills
//    (~45 us) so its FETCH_SIZE/VALUBusy finally show in the top-5 counters,
//    deciding L3-BW vs HBM-miss theory for the gather stream.
// Legacy 3-dispatch path kept as fallback (coop-launch failure / odd shapes).

#define D_FEAT 128
#define EPW 128           // legacy path: edges per wave
#define WAVES_PER_BLOCK 4
#define BLOCK_THREADS 256
#define COOP_BLOCKS 1024  // 4 blocks/CU at <=128 VGPR, co-residency guaranteed
#define PF 8

typedef float v2f __attribute__((ext_vector_type(2)));

__device__ __forceinline__ float bcast_f(float v, int j) {
    return __int_as_float(__builtin_amdgcn_readlane(__float_as_int(v), j));
}

__device__ __forceinline__ unsigned short f2bf_rne(float f) {
    unsigned int b = __float_as_uint(f);
    b += 0x7fffu + ((b >> 16) & 1u);
    return (unsigned short)(b >> 16);
}

// ---------------------------------------------------------------------------
// Fused cooperative kernel: phase A (zero + convert + pack), grid sync,
// phase B (aggregate).
// ---------------------------------------------------------------------------
__global__ __launch_bounds__(BLOCK_THREADS) void fused_kernel(
    const float* __restrict__ x, const float* __restrict__ vals,
    const int* __restrict__ rows, const int* __restrict__ cols,
    unsigned short* __restrict__ xb, unsigned int* __restrict__ cv,
    float* __restrict__ out, int n4, int n_edges, int n_out4) {
    const int tid = blockIdx.x * BLOCK_THREADS + threadIdx.x;
    const int nth = gridDim.x * BLOCK_THREADS;

    // ---- phase A ----
    {
        float4 z = make_float4(0.f, 0.f, 0.f, 0.f);
        float4* __restrict__ oz = (float4*)out;
        for (int i = tid; i < n_out4; i += nth) oz[i] = z;

        const float4* __restrict__ x4 = (const float4*)x;
        ushort4* __restrict__ xo = (ushort4*)xb;
        for (int i = tid; i < n4; i += nth) {
            float4 f = x4[i];
            ushort4 o;
            o.x = f2bf_rne(f.x);
            o.y = f2bf_rne(f.y);
            o.z = f2bf_rne(f.z);
            o.w = f2bf_rne(f.w);
            xo[i] = o;
        }
        for (int e = tid; e < n_edges; e += nth)
            cv[e] = ((unsigned int)cols[e] << 16) | (unsigned int)f2bf_rne(vals[e]);
    }

    cg::this_grid().sync();

    // ---- phase B: R6 agg body over a balanced contiguous group partition ----
    const unsigned int* __restrict__ xbu = (const unsigned int*)xb;
    const int wave = blockIdx.x * WAVES_PER_BLOCK + (threadIdx.x >> 6);
    const int lane = threadIdx.x & 63;

    const int n_g = n_edges >> 6;                  // # 64-edge groups
    const int n_w = gridDim.x * WAVES_PER_BLOCK;   // # waves
    const int gb = n_g / n_w, gr = n_g % n_w;
    const int myn = gb + (wave < gr ? 1 : 0);
    if (myn == 0) return;                          // after sync: safe
    const int gfirst = wave * gb + min(wave, gr);
    const int start = gfirst << 6;
    const int end = (gfirst + myn) << 6;

    const int first_row = rows[start];  // wave-uniform broadcast load
    float2 acc = make_float2(0.f, 0.f);
    int cur_row = first_row;

    for (int e0 = start; e0 < end; e0 += 64) {
        const unsigned int mycv = __builtin_nontemporal_load(cv + e0 + lane);
        const int myr = __builtin_nontemporal_load(rows + e0 + lane);
        const int nxt = __shfl(myr, (lane + 1) & 63);
        const unsigned long long bmask =
            __ballot(myr != nxt) & 0x7fffffffffffffffULL;  // bit63 at next grp
        const int grow0 = __builtin_amdgcn_readfirstlane(myr);
        if (grow0 != cur_row) {  // cur_row ended on previous group's edge #63
            float* o = out + (size_t)cur_row * D_FEAT + 2 * lane;
            if (cur_row == first_row) {
                atomicAdd(o, acc.x);
                atomicAdd(o + 1, acc.y);
            } else {
                v2f st; st.x = acc.x; st.y = acc.y;
                __builtin_nontemporal_store(st, (v2f*)o);
            }
            acc.x = 0.f; acc.y = 0.f;
            cur_row = grow0;
        }
#pragma unroll
        for (int j0 = 0; j0 < 64; j0 += PF) {
            unsigned int sv[PF];
            unsigned int xu[PF];
#pragma unroll
            for (int t = 0; t < PF; ++t) {  // PF independent gathers in flight
                sv[t] = (unsigned int)__builtin_amdgcn_readlane((int)mycv, j0 + t);
                xu[t] = xbu[(size_t)(sv[t] >> 16) * (D_FEAT / 2) + lane];
            }
#pragma unroll
            for (int t = 0; t < PF; ++t) {
                const float vf = __uint_as_float(sv[t] << 16);  // bf16 val
                acc.x = fmaf(vf, __uint_as_float(xu[t] << 16), acc.x);
                acc.y = fmaf(vf, __uint_as_float(xu[t] & 0xffff0000u), acc.y);
                if ((bmask >> (j0 + t)) & 1ULL) {  // row ends at this edge
                    const int fr = __builtin_amdgcn_readlane(myr, j0 + t);
                    float* o = out + (size_t)fr * D_FEAT + 2 * lane;
                    if (fr == first_row) {
                        atomicAdd(o, acc.x);
                        atomicAdd(o + 1, acc.y);
                    } else {
                        v2f st; st.x = acc.x; st.y = acc.y;
                        __builtin_nontemporal_store(st, (v2f*)o);
                    }
                    acc.x = 0.f; acc.y = 0.f;
                }
            }
        }
        cur_row = __builtin_amdgcn_readlane(myr, 63);
    }
    // Final row of the span: possibly shared with the next wave -> atomic.
    float* o = out + (size_t)cur_row * D_FEAT + 2 * lane;
    atomicAdd(o, acc.x);
    atomicAdd(o + 1, acc.y);
}

// ---------------------------------------------------------------------------
// Legacy path (fallback if cooperative launch is rejected): prep + agg.
// ---------------------------------------------------------------------------
__global__ __launch_bounds__(256) void prep_kernel(
    const float* __restrict__ x, const float* __restrict__ vals,
    const int* __restrict__ cols, unsigned short* __restrict__ xb,
    unsigned int* __restrict__ cv, int n4, int n_edges) {
    const int tid = blockIdx.x * blockDim.x + threadIdx.x;
    const int nth = gridDim.x * blockDim.x;
    const float4* __restrict__ x4 = (const float4*)x;
    ushort4* __restrict__ o4 = (ushort4*)xb;
    for (int i = tid; i < n4; i += nth) {
        float4 f = x4[i];
        ushort4 o;
        o.x = f2bf_rne(f.x);
        o.y = f2bf_rne(f.y);
        o.z = f2bf_rne(f.z);
        o.w = f2bf_rne(f.w);
        o4[i] = o;
    }
    for (int e = tid; e < n_edges; e += nth) {
        cv[e] = ((unsigned int)cols[e] << 16) | (unsigned int)f2bf_rne(vals[e]);
    }
}

__global__ __launch_bounds__(BLOCK_THREADS) void agg_bf16_kernel(
    const unsigned int* __restrict__ xb, const unsigned int* __restrict__ cv,
    const int* __restrict__ rows, float* __restrict__ out, int n_edges) {
    const int wave = blockIdx.x * WAVES_PER_BLOCK + (threadIdx.x >> 6);
    const int lane = threadIdx.x & 63;

    const int start = wave * EPW;
    if (start >= n_edges) return;
    const int end = min(start + EPW, n_edges);

    const int first_row = rows[start];
    float2 acc = make_float2(0.f, 0.f);
    int cur_row = first_row;

    for (int e0 = start; e0 < end; e0 += 64) {
        const unsigned int mycv = __builtin_nontemporal_load(cv + e0 + lane);
        const int myr = __builtin_nontemporal_load(rows + e0 + lane);
        const int nxt = __shfl(myr, (lane + 1) & 63);
        const unsigned long long bmask =
            __ballot(myr != nxt) & 0x7fffffffffffffffULL;
        const int g0 = __builtin_amdgcn_readfirstlane(myr);
        if (g0 != cur_row) {
            float* o = out + (size_t)cur_row * D_FEAT + 2 * lane;
            if (cur_row == first_row) {
                atomicAdd(o, acc.x);
                atomicAdd(o + 1, acc.y);
            } else {
                v2f st; st.x = acc.x; st.y = acc.y;
                __builtin_nontemporal_store(st, (v2f*)o);
            }
            acc.x = 0.f; acc.y = 0.f;
            cur_row = g0;
        }
#pragma unroll
        for (int j0 = 0; j0 < 64; j0 += PF) {
            unsigned int sv[PF];
            unsigned int xu[PF];
#pragma unroll
            for (int t = 0; t < PF; ++t) {
                sv[t] = (unsigned int)__builtin_amdgcn_readlane((int)mycv, j0 + t);
                xu[t] = xb[(size_t)(sv[t] >> 16) * (D_FEAT / 2) + lane];
            }
#pragma unroll
            for (int t = 0; t < PF; ++t) {
                const float vf = __uint_as_float(sv[t] << 16);
                acc.x = fmaf(vf, __uint_as_float(xu[t] << 16), acc.x);
                acc.y = fmaf(vf, __uint_as_float(xu[t] & 0xffff0000u), acc.y);
                if ((bmask >> (j0 + t)) & 1ULL) {
                    const int fr = __builtin_amdgcn_readlane(myr, j0 + t);
                    float* o = out + (size_t)fr * D_FEAT + 2 * lane;
                    if (fr == first_row) {
                        atomicAdd(o, acc.x);
                        atomicAdd(o + 1, acc.y);
                    } else {
                        v2f st; st.x = acc.x; st.y = acc.y;
                        __builtin_nontemporal_store(st, (v2f*)o);
                    }
                    acc.x = 0.f; acc.y = 0.f;
                }
            }
        }
        cur_row = __builtin_amdgcn_readlane(myr, 63);
    }
    float* o = out + (size_t)cur_row * D_FEAT + 2 * lane;
    atomicAdd(o, acc.x);
    atomicAdd(o + 1, acc.y);
}

// Fallback (R3-proven fp32 atomic path) for unexpected shapes / small ws.
__global__ __launch_bounds__(BLOCK_THREADS) void agg_f32_kernel(
    const float* __restrict__ x, const float* __restrict__ vals,
    const int* __restrict__ rows, const int* __restrict__ cols,
    float* __restrict__ out, int n_edges, int epw) {
    const int wave = blockIdx.x * WAVES_PER_BLOCK + (threadIdx.x >> 6);
    const int lane = threadIdx.x & 63;

    const int start = wave * epw;
    if (start >= n_edges) return;
    int end = start + epw;
    if (end > n_edges) end = n_edges;

    const float2* __restrict__ x2 = (const float2*)x;
    const int first_row = rows[start];
    const int last_row  = rows[end - 1];

    float2 acc = make_float2(0.f, 0.f);
    int cur_row = first_row;

    for (int e0 = start; e0 < end; e0 += 64) {
        const int nb = min(end - e0, 64);
        int myc = 0, myr = 0;
        float myv = 0.f;
        if (lane < nb) {
            myc = cols[e0 + lane];
            myr = rows[e0 + lane];
            myv = vals[e0 + lane];
        }
        for (int j0 = 0; j0 < nb; j0 += PF) {
            const int m = min(nb - j0, PF);
            float2 xv[PF];
            int    rj[PF];
            float  vj[PF];
#pragma unroll
            for (int t = 0; t < PF; ++t) {
                if (t < m) {
                    const int cj = __builtin_amdgcn_readlane(myc, j0 + t);
                    rj[t] = __builtin_amdgcn_readlane(myr, j0 + t);
                    vj[t] = bcast_f(myv, j0 + t);
                    xv[t] = x2[(size_t)cj * (D_FEAT / 2) + lane];
                }
            }
#pragma unroll
            for (int t = 0; t < PF; ++t) {
                if (t < m) {
                    if (rj[t] != cur_row) {
                        float* o = out + (size_t)cur_row * D_FEAT + 2 * lane;
                        if (cur_row == first_row || cur_row == last_row) {
                            atomicAdd(o,     acc.x);
                            atomicAdd(o + 1, acc.y);
                        } else {
                            v2f st; st.x = acc.x; st.y = acc.y;
                            __builtin_nontemporal_store(st, (v2f*)o);
                        }
                        acc.x = 0.f; acc.y = 0.f;
                        cur_row = rj[t];
                    }
                    acc.x = fmaf(vj[t], xv[t].x, acc.x);
                    acc.y = fmaf(vj[t], xv[t].y, acc.y);
                }
            }
        }
    }
    float* o = out + (size_t)cur_row * D_FEAT + 2 * lane;
    atomicAdd(o,     acc.x);
    atomicAdd(o + 1, acc.y);
}

extern "C" void kernel_launch(void* const* d_in, const int* in_sizes, int n_in,
                              void* d_out, int out_size, void* d_ws, size_t ws_size,
                              hipStream_t stream) {
    const float* x    = (const float*)d_in[0];
    const float* vals = (const float*)d_in[1];
    const int*   rows = (const int*)d_in[2];
    const int*   cols = (const int*)d_in[3];
    float*       out  = (float*)d_out;

    const int n_edges = in_sizes[1];
    const int n_x     = in_sizes[0];          // N*D floats
    const int n_nodes = out_size / D_FEAT;    // N

    const size_t xb_bytes = (size_t)n_x * sizeof(unsigned short);
    const size_t cv_off   = (xb_bytes + 255) & ~(size_t)255;
    const size_t need     = cv_off + (size_t)n_edges * sizeof(unsigned int);

    const bool fast_ok = (ws_size >= need) && (n_edges % 64 == 0) &&
                         (n_nodes <= 65536) && (n_x % 4 == 0) &&
                         (out_size % 4 == 0);

    if (fast_ok) {
        unsigned short* xb = (unsigned short*)d_ws;
        unsigned int*   cv = (unsigned int*)((char*)d_ws + cv_off);
        int n4 = n_x / 4, ne = n_edges, n_out4 = out_size / 4;
        void* args[] = {(void*)&x,  (void*)&vals, (void*)&rows, (void*)&cols,
                        (void*)&xb, (void*)&cv,   (void*)&out,
                        (void*)&n4, (void*)&ne,   (void*)&n_out4};
        hipError_t err = hipLaunchCooperativeKernel(
            fused_kernel, dim3(COOP_BLOCKS), dim3(BLOCK_THREADS), args, 0,
            stream);
        if (err == hipSuccess) return;
        // Cooperative launch rejected (e.g. under capture): legacy path.
        (void)hipMemsetAsync(d_out, 0, (size_t)out_size * sizeof(float), stream);
        prep_kernel<<<2048, 256, 0, stream>>>(x, vals, cols, xb, cv,
                                              n4, n_edges);
        const int waves  = (n_edges + EPW - 1) / EPW;
        const int blocks = (waves + WAVES_PER_BLOCK - 1) / WAVES_PER_BLOCK;
        agg_bf16_kernel<<<blocks, BLOCK_THREADS, 0, stream>>>(
            (const unsigned int*)xb, cv, rows, out, n_edges);
        return;
    }

    (void)hipMemsetAsync(d_out, 0, (size_t)out_size * sizeof(float), stream);
    const int total_waves = 8192;
    const int epw    = (n_edges + total_waves - 1) / total_waves;
    const int blocks = total_waves / WAVES_PER_BLOCK;
    agg_f32_kernel<<<blocks, BLOCK_THREADS, 0, stream>>>(
        x, vals, rows, cols, out, n_edges, epw);
}

// Round 3
// 118.256 us; speedup vs baseline: 2.1253x; 2.1253x over previous
//
#include <hip/hip_runtime.h>

// out = A @ x, COO (rows sorted), E=800000, N=50000, D=128.
// R11 = R10 resubmitted (R10 bench failed on container acquisition, never ran).
// Revert R9's cooperative fusion (16 waves/CU co-residency cap starved the
// gather of TLP: VALUBusy 5.5%, 932 GB/s, 177 us). Proven 2-dispatch static
// edge-balanced structure, with two targeted changes vs the 119.7 us baseline:
//  (1) prep also zeroes out (float4 grid-stride) -> memset dispatch removed.
//  (2) agg PF 8 -> 16: doubles outstanding row-gathers per wave (MLP), since
//      R9's counters show the gather phase is latency-bound, not byte-bound.
// agg: wave owns 128 edges (E%128==0 -> perfect balance). Per 64-edge group:
// one ballot(row!=next_row) gives a flush bitmask; one readlane per edge
// broadcasts packed (col,val); gather 2 bf16 dims/lane; fp32 acc. Interior
// rows: sole writer -> NT store. First/final rows of the wave range:
// atomicAdd onto zeroed out.

#define D_FEAT 128
#define EPW 128           // edges per wave (multiple of 64)
#define WAVES_PER_BLOCK 4
#define BLOCK_THREADS 256
#define PF 16             // gathers in flight per chunk (R10: 8 -> 16)

typedef float v2f __attribute__((ext_vector_type(2)));

__device__ __forceinline__ float bcast_f(float v, int j) {
    return __int_as_float(__builtin_amdgcn_readlane(__float_as_int(v), j));
}

__device__ __forceinline__ unsigned short f2bf_rne(float f) {
    unsigned int b = __float_as_uint(f);
    b += 0x7fffu + ((b >> 16) & 1u);
    return (unsigned short)(b >> 16);
}

// prep: zero out + x fp32->bf16 + pack (col<<16)|bf16(val).
__global__ __launch_bounds__(256) void prep_kernel(
    const float* __restrict__ x, const float* __restrict__ vals,
    const int* __restrict__ cols, unsigned short* __restrict__ xb,
    unsigned int* __restrict__ cv, float* __restrict__ out,
    int n4, int n_edges, int n_out4) {
    const int tid = blockIdx.x * blockDim.x + threadIdx.x;
    const int nth = gridDim.x * blockDim.x;
    // (a) zero the output (replaces hipMemsetAsync dispatch)
    float4 z = make_float4(0.f, 0.f, 0.f, 0.f);
    float4* __restrict__ oz = (float4*)out;
    for (int i = tid; i < n_out4; i += nth) oz[i] = z;
    // (b) x fp32 -> bf16 (RNE), float4 -> ushort4
    const float4* __restrict__ x4 = (const float4*)x;
    ushort4* __restrict__ o4 = (ushort4*)xb;
    for (int i = tid; i < n4; i += nth) {
        float4 f = x4[i];
        ushort4 o;
        o.x = f2bf_rne(f.x);
        o.y = f2bf_rne(f.y);
        o.z = f2bf_rne(f.z);
        o.w = f2bf_rne(f.w);
        o4[i] = o;
    }
    // (c) pack (col<<16) | bf16(val)
    for (int e = tid; e < n_edges; e += nth) {
        cv[e] = ((unsigned int)cols[e] << 16) | (unsigned int)f2bf_rne(vals[e]);
    }
}

__global__ __launch_bounds__(BLOCK_THREADS) void agg_bf16_kernel(
    const unsigned int* __restrict__ xb,  // [N][64] uints, 2 bf16 each
    const unsigned int* __restrict__ cv,  // [E] packed (col<<16)|bf16(val)
    const int* __restrict__ rows, float* __restrict__ out, int n_edges) {
    const int wave = blockIdx.x * WAVES_PER_BLOCK + (threadIdx.x >> 6);
    const int lane = threadIdx.x & 63;

    const int start = wave * EPW;
    if (start >= n_edges) return;
    const int end = min(start + EPW, n_edges);  // multiple of 64 by host guard

    const int first_row = rows[start];  // wave-uniform broadcast load
    float2 acc = make_float2(0.f, 0.f);
    int cur_row = first_row;

    for (int e0 = start; e0 < end; e0 += 64) {
        const unsigned int mycv = __builtin_nontemporal_load(cv + e0 + lane);
        const int myr = __builtin_nontemporal_load(rows + e0 + lane);
        const int nxt = __shfl(myr, (lane + 1) & 63);
        const unsigned long long bmask =
            __ballot(myr != nxt) & 0x7fffffffffffffffULL;  // bit63 handled at
                                                           // next group start
        const int g0 = __builtin_amdgcn_readfirstlane(myr);
        if (g0 != cur_row) {  // cur_row's last edge was previous group's #63
            float* o = out + (size_t)cur_row * D_FEAT + 2 * lane;
            if (cur_row == first_row) {
                atomicAdd(o, acc.x);
                atomicAdd(o + 1, acc.y);
            } else {
                v2f st; st.x = acc.x; st.y = acc.y;
                __builtin_nontemporal_store(st, (v2f*)o);
            }
            acc.x = 0.f; acc.y = 0.f;
            cur_row = g0;
        }
#pragma unroll
        for (int j0 = 0; j0 < 64; j0 += PF) {
            unsigned int sv[PF];
            unsigned int xu[PF];
#pragma unroll
            for (int t = 0; t < PF; ++t) {  // issue PF independent gathers
                sv[t] = (unsigned int)__builtin_amdgcn_readlane((int)mycv, j0 + t);
                xu[t] = xb[(size_t)(sv[t] >> 16) * (D_FEAT / 2) + lane];
            }
#pragma unroll
            for (int t = 0; t < PF; ++t) {
                const float vf = __uint_as_float(sv[t] << 16);  // bf16 val
                acc.x = fmaf(vf, __uint_as_float(xu[t] << 16), acc.x);
                acc.y = fmaf(vf, __uint_as_float(xu[t] & 0xffff0000u), acc.y);
                if ((bmask >> (j0 + t)) & 1ULL) {  // row ends at this edge
                    const int fr = __builtin_amdgcn_readlane(myr, j0 + t);
                    float* o = out + (size_t)fr * D_FEAT + 2 * lane;
                    if (fr == first_row) {
                        atomicAdd(o, acc.x);
                        atomicAdd(o + 1, acc.y);
                    } else {
                        v2f st; st.x = acc.x; st.y = acc.y;
                        __builtin_nontemporal_store(st, (v2f*)o);
                    }
                    acc.x = 0.f; acc.y = 0.f;
                }
            }
        }
        cur_row = __builtin_amdgcn_readlane(myr, 63);
    }
    // Final row of the range: possibly shared with the next wave -> atomic.
    float* o = out + (size_t)cur_row * D_FEAT + 2 * lane;
    atomicAdd(o, acc.x);
    atomicAdd(o + 1, acc.y);
}

// Fallback (R3-proven fp32 atomic path) for unexpected shapes / small ws.
__global__ __launch_bounds__(BLOCK_THREADS) void agg_f32_kernel(
    const float* __restrict__ x, const float* __restrict__ vals,
    const int* __restrict__ rows, const int* __restrict__ cols,
    float* __restrict__ out, int n_edges, int epw) {
    const int wave = blockIdx.x * WAVES_PER_BLOCK + (threadIdx.x >> 6);
    const int lane = threadIdx.x & 63;

    const int start = wave * epw;
    if (start >= n_edges) return;
    int end = start + epw;
    if (end > n_edges) end = n_edges;

    const float2* __restrict__ x2 = (const float2*)x;
    const int first_row = rows[start];
    const int last_row  = rows[end - 1];

    float2 acc = make_float2(0.f, 0.f);
    int cur_row = first_row;

    for (int e0 = start; e0 < end; e0 += 64) {
        const int nb = min(end - e0, 64);
        int myc = 0, myr = 0;
        float myv = 0.f;
        if (lane < nb) {
            myc = cols[e0 + lane];
            myr = rows[e0 + lane];
            myv = vals[e0 + lane];
        }
        for (int j0 = 0; j0 < nb; j0 += PF) {
            const int m = min(nb - j0, PF);
            float2 xv[PF];
            int    rj[PF];
            float  vj[PF];
#pragma unroll
            for (int t = 0; t < PF; ++t) {
                if (t < m) {
                    const int cj = __builtin_amdgcn_readlane(myc, j0 + t);
                    rj[t] = __builtin_amdgcn_readlane(myr, j0 + t);
                    vj[t] = bcast_f(myv, j0 + t);
                    xv[t] = x2[(size_t)cj * (D_FEAT / 2) + lane];
                }
            }
#pragma unroll
            for (int t = 0; t < PF; ++t) {
                if (t < m) {
                    if (rj[t] != cur_row) {
                        float* o = out + (size_t)cur_row * D_FEAT + 2 * lane;
                        if (cur_row == first_row || cur_row == last_row) {
                            atomicAdd(o,     acc.x);
                            atomicAdd(o + 1, acc.y);
                        } else {
                            v2f st; st.x = acc.x; st.y = acc.y;
                            __builtin_nontemporal_store(st, (v2f*)o);
                        }
                        acc.x = 0.f; acc.y = 0.f;
                        cur_row = rj[t];
                    }
                    acc.x = fmaf(vj[t], xv[t].x, acc.x);
                    acc.y = fmaf(vj[t], xv[t].y, acc.y);
                }
            }
        }
    }
    float* o = out + (size_t)cur_row * D_FEAT + 2 * lane;
    atomicAdd(o,     acc.x);
    atomicAdd(o + 1, acc.y);
}

extern "C" void kernel_launch(void* const* d_in, const int* in_sizes, int n_in,
                              void* d_out, int out_size, void* d_ws, size_t ws_size,
                              hipStream_t stream) {
    const float* x    = (const float*)d_in[0];
    const float* vals = (const float*)d_in[1];
    const int*   rows = (const int*)d_in[2];
    const int*   cols = (const int*)d_in[3];
    float*       out  = (float*)d_out;

    const int n_edges = in_sizes[1];
    const int n_x     = in_sizes[0];          // N*D floats
    const int n_nodes = out_size / D_FEAT;    // N

    const size_t xb_bytes = (size_t)n_x * sizeof(unsigned short);
    const size_t cv_off   = (xb_bytes + 255) & ~(size_t)255;
    const size_t need     = cv_off + (size_t)n_edges * sizeof(unsigned int);

    const bool fast_ok = (ws_size >= need) && (n_edges % 64 == 0) &&
                         (n_nodes <= 65536) && (n_x % 4 == 0) &&
                         (out_size % 4 == 0);

    if (fast_ok) {
        unsigned short* xb = (unsigned short*)d_ws;
        unsigned int*   cv = (unsigned int*)((char*)d_ws + cv_off);
        prep_kernel<<<2048, 256, 0, stream>>>(x, vals, cols, xb, cv, out,
                                              n_x / 4, n_edges, out_size / 4);
        const int waves  = (n_edges + EPW - 1) / EPW;
        const int blocks = (waves + WAVES_PER_BLOCK - 1) / WAVES_PER_BLOCK;
        agg_bf16_kernel<<<blocks, BLOCK_THREADS, 0, stream>>>(
            (const unsigned int*)xb, cv, rows, out, n_edges);
    } else {
        (void)hipMemsetAsync(d_out, 0, (size_t)out_size * sizeof(float), stream);
        const int total_waves = 8192;
        const int epw    = (n_edges + total_waves - 1) / total_waves;
        const int blocks = total_waves / WAVES_PER_BLOCK;
        agg_f32_kernel<<<blocks, BLOCK_THREADS, 0, stream>>>(
            x, vals, rows, cols, out, n_edges, epw);
    }
}